// Round 1
// baseline (465.181 us; speedup 1.0000x reference)
//
#include <hip/hip_runtime.h>

#define T_SEQ 2048
#define D_MODEL 1024
#define NH 16
#define HD 64
#define BH_TOT 32          // B*H
#define M_ROWS 4096        // B*T
#define SCALE 0.125f

typedef _Float16 h8 __attribute__((ext_vector_type(8)));
typedef _Float16 h4 __attribute__((ext_vector_type(4)));
typedef float f32x4 __attribute__((ext_vector_type(4)));

__device__ __forceinline__ f32x4 mfma_h(h8 a, h8 b, f32x4 c) {
    return __builtin_amdgcn_mfma_f32_16x16x32_f16(a, b, c, 0, 0, 0);
}

// ---------------- convert f32 -> f16 (flat) ----------------
__global__ void k_convert(const float* __restrict__ in, _Float16* __restrict__ out, int n) {
    int i = (blockIdx.x * blockDim.x + threadIdx.x) * 4;
    if (i < n) {
        float4 v = *(const float4*)(in + i);
        h4 o;
        o[0] = (_Float16)v.x; o[1] = (_Float16)v.y;
        o[2] = (_Float16)v.z; o[3] = (_Float16)v.w;
        *(h4*)(out + i) = o;
    }
}

// ---------------- transpose+convert: in [K][N] f32 -> out [N][K] f16 ----------------
__global__ void k_transpose(const float* __restrict__ in, _Float16* __restrict__ out, int K, int N) {
    __shared__ float tile[32][33];
    int nb = blockIdx.x * 32, kb = blockIdx.y * 32;
    int tx = threadIdx.x & 31, ty = threadIdx.x >> 5;   // 256 thr: ty 0..7
    #pragma unroll
    for (int i = 0; i < 32; i += 8)
        tile[ty + i][tx] = in[(size_t)(kb + ty + i) * N + (nb + tx)];
    __syncthreads();
    #pragma unroll
    for (int i = 0; i < 32; i += 8)
        out[(size_t)(nb + ty + i) * K + (kb + tx)] = (_Float16)tile[tx][ty + i];
}

// ---------------- GEMM: C = A[M,K] @ Bt[N,K]^T + bias ----------------
// MODE 0: scatter epilogue into Q/K/V/Vt/T f16 buffers ([B,H,T,HD], Vt=[B,H,HD,T])
// MODE 1: plain f32 output C[M,N] + bias
template<int MODE>
__launch_bounds__(256, 2)
__global__ void k_gemm(const _Float16* __restrict__ A, const _Float16* __restrict__ Bt,
                       int M, int N, int K, const float* __restrict__ bias,
                       _Float16* __restrict__ qo, _Float16* __restrict__ ko,
                       _Float16* __restrict__ vo, _Float16* __restrict__ vto,
                       _Float16* __restrict__ to, float* __restrict__ cOut)
{
    constexpr int LDT = 40;  // 80B row stride: 16B aligned, breaks bank pattern
    __shared__ __align__(16) _Float16 lA[128 * LDT];
    __shared__ __align__(16) _Float16 lB[128 * LDT];
    const int tid = threadIdx.x;
    const int wid = tid >> 6, lane = tid & 63, lrow = lane & 15, lg = lane >> 4;
    const int wm = wid >> 1, wn = wid & 1;
    const int m0 = blockIdx.x * 128, n0 = blockIdx.y * 128;

    f32x4 acc[4][4];
    #pragma unroll
    for (int i = 0; i < 4; i++)
        #pragma unroll
        for (int j = 0; j < 4; j++) acc[i][j] = (f32x4){0.f, 0.f, 0.f, 0.f};

    const int srow = tid >> 1, scol = (tid & 1) * 16;
    const _Float16* ga = A + (size_t)(m0 + srow) * K + scol;
    const _Float16* gb = Bt + (size_t)(n0 + srow) * K + scol;

    h8 ra0 = *(const h8*)ga, ra1 = *(const h8*)(ga + 8);
    h8 rb0 = *(const h8*)gb, rb1 = *(const h8*)(gb + 8);
    const int nk = K / 32;
    for (int kt = 0; kt < nk; ++kt) {
        *(h8*)&lA[srow * LDT + scol]     = ra0;
        *(h8*)&lA[srow * LDT + scol + 8] = ra1;
        *(h8*)&lB[srow * LDT + scol]     = rb0;
        *(h8*)&lB[srow * LDT + scol + 8] = rb1;
        __syncthreads();
        if (kt + 1 < nk) {
            ra0 = *(const h8*)(ga + (kt + 1) * 32);
            ra1 = *(const h8*)(ga + (kt + 1) * 32 + 8);
            rb0 = *(const h8*)(gb + (kt + 1) * 32);
            rb1 = *(const h8*)(gb + (kt + 1) * 32 + 8);
        }
        h8 af[4], bfr[4];
        #pragma unroll
        for (int mi = 0; mi < 4; mi++)
            af[mi] = *(const h8*)&lA[(wm * 64 + mi * 16 + lrow) * LDT + lg * 8];
        #pragma unroll
        for (int ni = 0; ni < 4; ni++)
            bfr[ni] = *(const h8*)&lB[(wn * 64 + ni * 16 + lrow) * LDT + lg * 8];
        #pragma unroll
        for (int mi = 0; mi < 4; mi++)
            #pragma unroll
            for (int ni = 0; ni < 4; ni++)
                acc[mi][ni] = mfma_h(af[mi], bfr[ni], acc[mi][ni]);
        __syncthreads();
    }

    if (MODE == 0) {
        const int ssel = n0 >> 10;  // block-uniform: which of q/k/v/t
        #pragma unroll
        for (int mi = 0; mi < 4; mi++) {
            #pragma unroll
            for (int ni = 0; ni < 4; ni++) {
                const int nn = n0 + wn * 64 + ni * 16 + lrow;
                const float bv = bias[nn];
                const int h = (nn >> 6) & 15, hd = nn & 63;
                #pragma unroll
                for (int r = 0; r < 4; r++) {
                    const int mm = m0 + wm * 64 + mi * 16 + 4 * lg + r;
                    const int b = mm >> 11, t = mm & (T_SEQ - 1);
                    const _Float16 hv = (_Float16)(acc[mi][ni][r] + bv);
                    const size_t idx = ((size_t)(b * NH + h) * T_SEQ + t) * HD + hd;
                    if (ssel == 0) qo[idx] = hv;
                    else if (ssel == 1) ko[idx] = hv;
                    else if (ssel == 2) {
                        vo[idx] = hv;
                        vto[((size_t)(b * NH + h) * HD + hd) * T_SEQ + t] = hv;
                    } else to[idx] = hv;
                }
            }
        }
    } else {
        #pragma unroll
        for (int mi = 0; mi < 4; mi++) {
            #pragma unroll
            for (int ni = 0; ni < 4; ni++) {
                const int nn = n0 + wn * 64 + ni * 16 + lrow;
                const float bv = bias[nn];
                #pragma unroll
                for (int r = 0; r < 4; r++) {
                    const int mm = m0 + wm * 64 + mi * 16 + 4 * lg + r;
                    cOut[(size_t)mm * N + nn] = acc[mi][ni][r] + bv;
                }
            }
        }
    }
}

// ---------------- kv_cum = SCALE * cumsum_t(k*v), per (b,h,d) ----------------
__global__ void k_kvcum(const _Float16* __restrict__ Kb, const _Float16* __restrict__ Vb,
                        _Float16* __restrict__ KVC)
{
    const int bh = blockIdx.x;
    const int w = threadIdx.x >> 6, lane = threadIdx.x & 63;
    const size_t base = (size_t)bh * T_SEQ * HD + lane;
    const int t0 = w * (T_SEQ / 4);
    float s = 0.f;
    for (int i = 0; i < T_SEQ / 4; i++) {
        size_t o = base + (size_t)(t0 + i) * HD;
        s += (float)Kb[o] * (float)Vb[o];
    }
    __shared__ float tot[4][64];
    tot[w][lane] = s;
    __syncthreads();
    float acc = 0.f;
    for (int ww = 0; ww < w; ww++) acc += tot[ww][lane];
    for (int i = 0; i < T_SEQ / 4; i++) {
        size_t o = base + (size_t)(t0 + i) * HD;
        acc += (float)Kb[o] * (float)Vb[o];
        KVC[o] = (_Float16)(acc * SCALE);
    }
}

// ---------------- flash attention with triplet term ----------------
// scores = SCALE*(Q.K^T) + SCALE*((Q*T).KVC^T); causal; softmax; O = P.V
__launch_bounds__(256, 2)
__global__ void k_attn(const _Float16* __restrict__ Qb, const _Float16* __restrict__ Kb,
                       const _Float16* __restrict__ KVC, const _Float16* __restrict__ Vt,
                       const _Float16* __restrict__ Tb, _Float16* __restrict__ AO)
{
    const int bh = blockIdx.y;
    const int q0 = blockIdx.x * 64;
    const int tid = threadIdx.x;
    const int wid = tid >> 6, lane = tid & 63, lrow = lane & 15, lg = lane >> 4;
    const size_t hb = (size_t)bh * T_SEQ * HD;
    const _Float16* qp = Qb + hb;
    const _Float16* kp = Kb + hb;
    const _Float16* cp = KVC + hb;
    const _Float16* tp = Tb + hb;
    const _Float16* vp = Vt + hb;    // [HD][T]

    __shared__ __align__(16) _Float16 lP[4][16 * 64];  // per-wave P buffer (swizzled)

    // hoisted Q / Q*T fragments, pre-scaled by SCALE
    const int qrow = q0 + wid * 16 + lrow;
    h8 qf[2], qtf[2];
    #pragma unroll
    for (int ks = 0; ks < 2; ++ks) {
        h8 qv = *(const h8*)&qp[(size_t)qrow * HD + ks * 32 + lg * 8];
        h8 tv = *(const h8*)&tp[(size_t)qrow * HD + ks * 32 + lg * 8];
        h8 a, b;
        #pragma unroll
        for (int i = 0; i < 8; i++) {
            float qq = (float)qv[i] * SCALE;
            a[i] = (_Float16)qq;
            b[i] = (_Float16)(qq * (float)tv[i]);
        }
        qf[ks] = a; qtf[ks] = b;
    }

    float m_r[4], l_r[4];
    f32x4 o[4];
    #pragma unroll
    for (int r = 0; r < 4; r++) { m_r[r] = -__builtin_inff(); l_r[r] = 0.f; }
    #pragma unroll
    for (int ct = 0; ct < 4; ct++) o[ct] = (f32x4){0.f, 0.f, 0.f, 0.f};

    const int jmax = q0 / 64;
    for (int j = 0; j <= jmax; ++j) {
        f32x4 s[4];
        #pragma unroll
        for (int ct = 0; ct < 4; ct++) s[ct] = (f32x4){0.f, 0.f, 0.f, 0.f};
        #pragma unroll
        for (int ct = 0; ct < 4; ct++) {
            const int krow = j * 64 + ct * 16 + lrow;
            #pragma unroll
            for (int ks = 0; ks < 2; ks++) {
                h8 kf = *(const h8*)&kp[(size_t)krow * HD + ks * 32 + lg * 8];
                s[ct] = mfma_h(qf[ks], kf, s[ct]);
                h8 cf = *(const h8*)&cp[(size_t)krow * HD + ks * 32 + lg * 8];
                s[ct] = mfma_h(qtf[ks], cf, s[ct]);
            }
        }
        if (j == jmax) {   // diagonal tile: causal mask
            #pragma unroll
            for (int ct = 0; ct < 4; ct++)
                #pragma unroll
                for (int r = 0; r < 4; r++) {
                    int key = j * 64 + ct * 16 + lrow;
                    int qr  = q0 + wid * 16 + 4 * lg + r;
                    if (key > qr) s[ct][r] = -__builtin_inff();
                }
        }
        // row max across 64 keys (16 lanes x 4 col-tiles)
        float mx[4];
        #pragma unroll
        for (int r = 0; r < 4; r++)
            mx[r] = fmaxf(fmaxf(s[0][r], s[1][r]), fmaxf(s[2][r], s[3][r]));
        #pragma unroll
        for (int d = 1; d < 16; d <<= 1)
            #pragma unroll
            for (int r = 0; r < 4; r++) mx[r] = fmaxf(mx[r], __shfl_xor(mx[r], d, 64));

        float mn[4], scl[4], rs[4];
        #pragma unroll
        for (int r = 0; r < 4; r++) {
            mn[r] = fmaxf(m_r[r], mx[r]);
            scl[r] = __expf(m_r[r] - mn[r]);
            rs[r] = 0.f;
        }
        // P = exp(s - m), write to swizzled LDS (wave-private)
        #pragma unroll
        for (int ct = 0; ct < 4; ct++) {
            const int col = ct * 16 + lrow;
            #pragma unroll
            for (int r = 0; r < 4; r++) {
                float p = __expf(s[ct][r] - mn[r]);
                rs[r] += p;
                const int row = 4 * lg + r;
                const int boff = row * 128 + ((col * 2) ^ ((row & 7) << 4));
                lP[wid][boff >> 1] = (_Float16)p;
            }
        }
        #pragma unroll
        for (int d = 1; d < 16; d <<= 1)
            #pragma unroll
            for (int r = 0; r < 4; r++) rs[r] += __shfl_xor(rs[r], d, 64);
        #pragma unroll
        for (int r = 0; r < 4; r++) { l_r[r] = l_r[r] * scl[r] + rs[r]; m_r[r] = mn[r]; }
        #pragma unroll
        for (int ct = 0; ct < 4; ct++)
            #pragma unroll
            for (int r = 0; r < 4; r++) o[ct][r] *= scl[r];

        // P fragments (A-layout) from swizzled LDS
        h8 pa[2];
        #pragma unroll
        for (int ks = 0; ks < 2; ks++) {
            const int boff = lrow * 128 + ((ks * 64 + lg * 16) ^ ((lrow & 7) << 4));
            pa[ks] = *(const h8*)((const char*)lP[wid] + boff);
        }
        // O += P @ V   (V fragments contiguous from Vt)
        #pragma unroll
        for (int ct = 0; ct < 4; ct++) {
            #pragma unroll
            for (int ks = 0; ks < 2; ks++) {
                h8 vf = *(const h8*)&vp[(size_t)(ct * 16 + lrow) * T_SEQ + j * 64 + ks * 32 + lg * 8];
                o[ct] = mfma_h(pa[ks], vf, o[ct]);
            }
        }
    }
    // normalize + write AO [b, t, h*64+d] f16
    const int b = bh >> 4, h = bh & 15;
    #pragma unroll
    for (int ct = 0; ct < 4; ct++)
        #pragma unroll
        for (int r = 0; r < 4; r++) {
            const int trow = q0 + wid * 16 + 4 * lg + r;
            const int d = ct * 16 + lrow;
            AO[((size_t)(b * T_SEQ + trow)) * D_MODEL + h * HD + d] =
                (_Float16)(o[ct][r] / l_r[r]);
        }
}

extern "C" void kernel_launch(void* const* d_in, const int* in_sizes, int n_in,
                              void* d_out, int out_size, void* d_ws, size_t ws_size,
                              hipStream_t stream)
{
    const float* x     = (const float*)d_in[0];
    const float* Wqkvt = (const float*)d_in[1];
    const float* bqkvt = (const float*)d_in[2];
    const float* Wout  = (const float*)d_in[3];
    const float* bout  = (const float*)d_in[4];
    float* out = (float*)d_out;

    char* ws = (char*)d_ws;
    size_t off = 0;
    auto alloc = [&](size_t bytes) {
        char* p = ws + off;
        off += (bytes + 255) & ~(size_t)255;
        return p;
    };
    const size_t SZ = (size_t)M_ROWS * D_MODEL * 2;   // 8 MiB per f16 [4096x1024] buffer
    _Float16* xb  = (_Float16*)alloc(SZ);
    _Float16* wt  = (_Float16*)alloc(SZ);
    _Float16* wo  = (_Float16*)alloc((size_t)D_MODEL * D_MODEL * 2);
    _Float16* Qh  = (_Float16*)alloc(SZ / 4);  // wait: per-tensor is B*H*T*HD = 4M el = 8MB
    // NOTE: B*H*T*HD = 2*16*2048*64 = 4,194,304 elements = 8 MiB in f16 — same as SZ.
    // Redo allocations properly below.
    (void)Qh; off = 0;
    xb  = (_Float16*)alloc(SZ);
    wt  = (_Float16*)alloc(SZ);
    wo  = (_Float16*)alloc((size_t)D_MODEL * D_MODEL * 2);
    _Float16* Qh2 = (_Float16*)alloc(SZ);
    _Float16* Kh  = (_Float16*)alloc(SZ);
    _Float16* Vh  = (_Float16*)alloc(SZ);
    _Float16* Vth = (_Float16*)alloc(SZ);
    _Float16* Th  = (_Float16*)alloc(SZ);
    _Float16* KVC = (_Float16*)alloc(SZ);
    _Float16* AO  = (_Float16*)alloc(SZ);

    k_convert<<<4096, 256, 0, stream>>>(x, xb, M_ROWS * D_MODEL);
    k_transpose<<<dim3(128, 32), 256, 0, stream>>>(Wqkvt, wt, D_MODEL, 4 * D_MODEL);
    k_transpose<<<dim3(32, 32), 256, 0, stream>>>(Wout, wo, D_MODEL, D_MODEL);
    k_gemm<0><<<dim3(32, 32), 256, 0, stream>>>(xb, wt, M_ROWS, 4 * D_MODEL, D_MODEL,
                                                bqkvt, Qh2, Kh, Vh, Vth, Th, nullptr);
    k_kvcum<<<BH_TOT, 256, 0, stream>>>(Kh, Vh, KVC);
    k_attn<<<dim3(T_SEQ / 64, BH_TOT), 256, 0, stream>>>(Qh2, Kh, KVC, Vth, Th, AO);
    k_gemm<1><<<dim3(32, 8), 256, 0, stream>>>(AO, wo, M_ROWS, D_MODEL, D_MODEL,
                                               bout, nullptr, nullptr, nullptr, nullptr,
                                               nullptr, out);
}

// Round 2
// 332.329 us; speedup vs baseline: 1.3998x; 1.3998x over previous
//
#include <hip/hip_runtime.h>

#define T_SEQ 2048
#define D_MODEL 1024
#define NH 16
#define HD 64
#define BH_TOT 32          // B*H
#define M_ROWS 4096        // B*T
#define NT 32              // number of 64-row q tiles
#define SCALE 0.125f

typedef _Float16 h8 __attribute__((ext_vector_type(8)));
typedef _Float16 h4 __attribute__((ext_vector_type(4)));
typedef float f32x4 __attribute__((ext_vector_type(4)));

__device__ __forceinline__ f32x4 mfma_h(h8 a, h8 b, f32x4 c) {
    return __builtin_amdgcn_mfma_f32_16x16x32_f16(a, b, c, 0, 0, 0);
}

// ---------------- convert f32 -> f16 (flat) ----------------
__global__ void k_convert(const float* __restrict__ in, _Float16* __restrict__ out, int n) {
    int i = (blockIdx.x * blockDim.x + threadIdx.x) * 4;
    if (i < n) {
        float4 v = *(const float4*)(in + i);
        h4 o;
        o[0] = (_Float16)v.x; o[1] = (_Float16)v.y;
        o[2] = (_Float16)v.z; o[3] = (_Float16)v.w;
        *(h4*)(out + i) = o;
    }
}

// ---------------- transpose+convert: in [K][N] f32 -> out [N][K] f16 ----------------
__global__ void k_transpose(const float* __restrict__ in, _Float16* __restrict__ out, int K, int N) {
    __shared__ float tile[32][33];
    int nb = blockIdx.x * 32, kb = blockIdx.y * 32;
    int tx = threadIdx.x & 31, ty = threadIdx.x >> 5;   // 256 thr: ty 0..7
    #pragma unroll
    for (int i = 0; i < 32; i += 8)
        tile[ty + i][tx] = in[(size_t)(kb + ty + i) * N + (nb + tx)];
    __syncthreads();
    #pragma unroll
    for (int i = 0; i < 32; i += 8)
        out[(size_t)(nb + ty + i) * K + (kb + tx)] = (_Float16)tile[tx][ty + i];
}

// ---------------- GEMM: C = A[M,K] @ Bt[N,K]^T + bias ----------------
// MODE 0: scatter epilogue into Q/K/V/Vt/T f16 buffers ([B,H,T,HD], Vt=[B,H,HD,T])
// MODE 1: plain f32 output C[M,N] + bias
template<int MODE>
__launch_bounds__(256, 2)
__global__ void k_gemm(const _Float16* __restrict__ A, const _Float16* __restrict__ Bt,
                       int M, int N, int K, const float* __restrict__ bias,
                       _Float16* __restrict__ qo, _Float16* __restrict__ ko,
                       _Float16* __restrict__ vo, _Float16* __restrict__ vto,
                       _Float16* __restrict__ to, float* __restrict__ cOut)
{
    constexpr int LDT = 40;  // 80B row stride: 16B aligned, breaks bank pattern
    __shared__ __align__(16) _Float16 lA[128 * LDT];
    __shared__ __align__(16) _Float16 lB[128 * LDT];
    const int tid = threadIdx.x;
    const int wid = tid >> 6, lane = tid & 63, lrow = lane & 15, lg = lane >> 4;
    const int wm = wid >> 1, wn = wid & 1;
    const int m0 = blockIdx.x * 128, n0 = blockIdx.y * 128;

    f32x4 acc[4][4];
    #pragma unroll
    for (int i = 0; i < 4; i++)
        #pragma unroll
        for (int j = 0; j < 4; j++) acc[i][j] = (f32x4){0.f, 0.f, 0.f, 0.f};

    const int srow = tid >> 1, scol = (tid & 1) * 16;
    const _Float16* ga = A + (size_t)(m0 + srow) * K + scol;
    const _Float16* gb = Bt + (size_t)(n0 + srow) * K + scol;

    h8 ra0 = *(const h8*)ga, ra1 = *(const h8*)(ga + 8);
    h8 rb0 = *(const h8*)gb, rb1 = *(const h8*)(gb + 8);
    const int nk = K / 32;
    for (int kt = 0; kt < nk; ++kt) {
        *(h8*)&lA[srow * LDT + scol]     = ra0;
        *(h8*)&lA[srow * LDT + scol + 8] = ra1;
        *(h8*)&lB[srow * LDT + scol]     = rb0;
        *(h8*)&lB[srow * LDT + scol + 8] = rb1;
        __syncthreads();
        if (kt + 1 < nk) {
            ra0 = *(const h8*)(ga + (kt + 1) * 32);
            ra1 = *(const h8*)(ga + (kt + 1) * 32 + 8);
            rb0 = *(const h8*)(gb + (kt + 1) * 32);
            rb1 = *(const h8*)(gb + (kt + 1) * 32 + 8);
        }
        h8 af[4], bfr[4];
        #pragma unroll
        for (int mi = 0; mi < 4; mi++)
            af[mi] = *(const h8*)&lA[(wm * 64 + mi * 16 + lrow) * LDT + lg * 8];
        #pragma unroll
        for (int ni = 0; ni < 4; ni++)
            bfr[ni] = *(const h8*)&lB[(wn * 64 + ni * 16 + lrow) * LDT + lg * 8];
        #pragma unroll
        for (int mi = 0; mi < 4; mi++)
            #pragma unroll
            for (int ni = 0; ni < 4; ni++)
                acc[mi][ni] = mfma_h(af[mi], bfr[ni], acc[mi][ni]);
        __syncthreads();
    }

    if (MODE == 0) {
        const int ssel = n0 >> 10;  // block-uniform: which of q/k/v/t
        #pragma unroll
        for (int mi = 0; mi < 4; mi++) {
            #pragma unroll
            for (int ni = 0; ni < 4; ni++) {
                const int nn = n0 + wn * 64 + ni * 16 + lrow;
                const float bv = bias[nn];
                const int h = (nn >> 6) & 15, hd = nn & 63;
                #pragma unroll
                for (int r = 0; r < 4; r++) {
                    const int mm = m0 + wm * 64 + mi * 16 + 4 * lg + r;
                    const int b = mm >> 11, t = mm & (T_SEQ - 1);
                    const _Float16 hv = (_Float16)(acc[mi][ni][r] + bv);
                    const size_t idx = ((size_t)(b * NH + h) * T_SEQ + t) * HD + hd;
                    if (ssel == 0) qo[idx] = hv;
                    else if (ssel == 1) ko[idx] = hv;
                    else if (ssel == 2) {
                        vo[idx] = hv;
                        vto[((size_t)(b * NH + h) * HD + hd) * T_SEQ + t] = hv;
                    } else to[idx] = hv;
                }
            }
        }
    } else {
        #pragma unroll
        for (int mi = 0; mi < 4; mi++) {
            #pragma unroll
            for (int ni = 0; ni < 4; ni++) {
                const int nn = n0 + wn * 64 + ni * 16 + lrow;
                const float bv = bias[nn];
                #pragma unroll
                for (int r = 0; r < 4; r++) {
                    const int mm = m0 + wm * 64 + mi * 16 + 4 * lg + r;
                    cOut[(size_t)mm * N + nn] = acc[mi][ni][r] + bv;
                }
            }
        }
    }
}

// ---------------- kv_cum = SCALE * cumsum_t(k*v), per (b,h,d) ----------------
__global__ void k_kvcum(const _Float16* __restrict__ Kb, const _Float16* __restrict__ Vb,
                        _Float16* __restrict__ KVC)
{
    const int bh = blockIdx.x;
    const int w = threadIdx.x >> 6, lane = threadIdx.x & 63;
    const size_t base = (size_t)bh * T_SEQ * HD + lane;
    const int t0 = w * (T_SEQ / 4);
    float s = 0.f;
    for (int i = 0; i < T_SEQ / 4; i++) {
        size_t o = base + (size_t)(t0 + i) * HD;
        s += (float)Kb[o] * (float)Vb[o];
    }
    __shared__ float tot[4][64];
    tot[w][lane] = s;
    __syncthreads();
    float acc = 0.f;
    for (int ww = 0; ww < w; ww++) acc += tot[ww][lane];
    for (int i = 0; i < T_SEQ / 4; i++) {
        size_t o = base + (size_t)(t0 + i) * HD;
        acc += (float)Kb[o] * (float)Vb[o];
        KVC[o] = (_Float16)(acc * SCALE);
    }
}

// ---------------- flash attention with triplet term ----------------
// scores = SCALE*(Q.K^T) + SCALE*((Q*T).KVC^T); causal; softmax; O = P.V
// Balanced: block (bh, p) processes q-tiles p and NT-1-p -> exactly NT+1 key-tile
// iterations per block, uniform across the whole grid.
__launch_bounds__(256, 4)
__global__ void k_attn(const _Float16* __restrict__ Qb, const _Float16* __restrict__ Kb,
                       const _Float16* __restrict__ KVC, const _Float16* __restrict__ Vt,
                       const _Float16* __restrict__ Tb, _Float16* __restrict__ AO)
{
    const int bh = blockIdx.x;
    const int pair = blockIdx.y;    // 0..NT/2-1
    const int tid = threadIdx.x;
    const int wid = tid >> 6, lane = tid & 63, lrow = lane & 15, lg = lane >> 4;
    const size_t hb = (size_t)bh * T_SEQ * HD;
    const _Float16* qp = Qb + hb;
    const _Float16* kp = Kb + hb;
    const _Float16* cp = KVC + hb;
    const _Float16* tp = Tb + hb;
    const _Float16* vp = Vt + hb;    // [HD][T]
    const int b = bh >> 4, h = bh & 15;

    __shared__ __align__(16) _Float16 lP[4][16 * 64];  // per-wave P buffer (swizzled)

    for (int half = 0; half < 2; ++half) {
        const int qi = half ? (NT - 1 - pair) : pair;
        const int q0 = qi * 64;

        // hoisted Q / Q*T fragments, pre-scaled by SCALE
        const int qrow = q0 + wid * 16 + lrow;
        h8 qf[2], qtf[2];
        #pragma unroll
        for (int ks = 0; ks < 2; ++ks) {
            h8 qv = *(const h8*)&qp[(size_t)qrow * HD + ks * 32 + lg * 8];
            h8 tv = *(const h8*)&tp[(size_t)qrow * HD + ks * 32 + lg * 8];
            h8 a2, b2;
            #pragma unroll
            for (int i = 0; i < 8; i++) {
                float qq = (float)qv[i] * SCALE;
                a2[i] = (_Float16)qq;
                b2[i] = (_Float16)(qq * (float)tv[i]);
            }
            qf[ks] = a2; qtf[ks] = b2;
        }

        float m_r[4], l_r[4];
        f32x4 o[4];
        #pragma unroll
        for (int r = 0; r < 4; r++) { m_r[r] = -__builtin_inff(); l_r[r] = 0.f; }
        #pragma unroll
        for (int ct = 0; ct < 4; ct++) o[ct] = (f32x4){0.f, 0.f, 0.f, 0.f};

        const int jmax = qi;
        for (int j = 0; j <= jmax; ++j) {
            f32x4 s[4];
            #pragma unroll
            for (int ct = 0; ct < 4; ct++) s[ct] = (f32x4){0.f, 0.f, 0.f, 0.f};
            #pragma unroll
            for (int ct = 0; ct < 4; ct++) {
                const int krow = j * 64 + ct * 16 + lrow;
                #pragma unroll
                for (int ks = 0; ks < 2; ks++) {
                    h8 kf = *(const h8*)&kp[(size_t)krow * HD + ks * 32 + lg * 8];
                    s[ct] = mfma_h(qf[ks], kf, s[ct]);
                    h8 cf = *(const h8*)&cp[(size_t)krow * HD + ks * 32 + lg * 8];
                    s[ct] = mfma_h(qtf[ks], cf, s[ct]);
                }
            }
            if (j == jmax) {   // diagonal tile: causal mask
                #pragma unroll
                for (int ct = 0; ct < 4; ct++)
                    #pragma unroll
                    for (int r = 0; r < 4; r++) {
                        int key = j * 64 + ct * 16 + lrow;
                        int qr  = q0 + wid * 16 + 4 * lg + r;
                        if (key > qr) s[ct][r] = -__builtin_inff();
                    }
            }
            // row max across 64 keys (16 lanes x 4 col-tiles)
            float mx[4];
            #pragma unroll
            for (int r = 0; r < 4; r++)
                mx[r] = fmaxf(fmaxf(s[0][r], s[1][r]), fmaxf(s[2][r], s[3][r]));
            #pragma unroll
            for (int d = 1; d < 16; d <<= 1)
                #pragma unroll
                for (int r = 0; r < 4; r++) mx[r] = fmaxf(mx[r], __shfl_xor(mx[r], d, 64));

            float mn[4], scl[4], rs[4];
            #pragma unroll
            for (int r = 0; r < 4; r++) {
                mn[r] = fmaxf(m_r[r], mx[r]);
                scl[r] = __expf(m_r[r] - mn[r]);
                rs[r] = 0.f;
            }
            // P = exp(s - m), write to swizzled LDS (wave-private)
            #pragma unroll
            for (int ct = 0; ct < 4; ct++) {
                const int col = ct * 16 + lrow;
                #pragma unroll
                for (int r = 0; r < 4; r++) {
                    float p = __expf(s[ct][r] - mn[r]);
                    rs[r] += p;
                    const int row = 4 * lg + r;
                    const int boff = row * 128 + ((col * 2) ^ ((row & 7) << 4));
                    lP[wid][boff >> 1] = (_Float16)p;
                }
            }
            #pragma unroll
            for (int d = 1; d < 16; d <<= 1)
                #pragma unroll
                for (int r = 0; r < 4; r++) rs[r] += __shfl_xor(rs[r], d, 64);
            #pragma unroll
            for (int r = 0; r < 4; r++) { l_r[r] = l_r[r] * scl[r] + rs[r]; m_r[r] = mn[r]; }
            #pragma unroll
            for (int ct = 0; ct < 4; ct++)
                #pragma unroll
                for (int r = 0; r < 4; r++) o[ct][r] *= scl[r];

            // P fragments (A-layout) from swizzled LDS
            h8 pa[2];
            #pragma unroll
            for (int ks = 0; ks < 2; ks++) {
                const int boff = lrow * 128 + ((ks * 64 + lg * 16) ^ ((lrow & 7) << 4));
                pa[ks] = *(const h8*)((const char*)lP[wid] + boff);
            }
            // O += P @ V   (V fragments contiguous from Vt)
            #pragma unroll
            for (int ct = 0; ct < 4; ct++) {
                #pragma unroll
                for (int ks = 0; ks < 2; ks++) {
                    h8 vf = *(const h8*)&vp[(size_t)(ct * 16 + lrow) * T_SEQ + j * 64 + ks * 32 + lg * 8];
                    o[ct] = mfma_h(pa[ks], vf, o[ct]);
                }
            }
        }
        // normalize + write AO [b, t, h*64+d] f16
        #pragma unroll
        for (int ct = 0; ct < 4; ct++)
            #pragma unroll
            for (int r = 0; r < 4; r++) {
                const int trow = q0 + wid * 16 + 4 * lg + r;
                const int d = ct * 16 + lrow;
                AO[((size_t)(b * T_SEQ + trow)) * D_MODEL + h * HD + d] =
                    (_Float16)(o[ct][r] / l_r[r]);
            }
    }
}

extern "C" void kernel_launch(void* const* d_in, const int* in_sizes, int n_in,
                              void* d_out, int out_size, void* d_ws, size_t ws_size,
                              hipStream_t stream)
{
    const float* x     = (const float*)d_in[0];
    const float* Wqkvt = (const float*)d_in[1];
    const float* bqkvt = (const float*)d_in[2];
    const float* Wout  = (const float*)d_in[3];
    const float* bout  = (const float*)d_in[4];
    float* out = (float*)d_out;

    char* ws = (char*)d_ws;
    size_t off = 0;
    auto alloc = [&](size_t bytes) {
        char* p = ws + off;
        off += (bytes + 255) & ~(size_t)255;
        return p;
    };
    const size_t SZ = (size_t)M_ROWS * D_MODEL * 2;   // 8 MiB per f16 buffer
    _Float16* xb  = (_Float16*)alloc(SZ);
    _Float16* wt  = (_Float16*)alloc(SZ);
    _Float16* wo  = (_Float16*)alloc((size_t)D_MODEL * D_MODEL * 2);
    _Float16* Qh  = (_Float16*)alloc(SZ);
    _Float16* Kh  = (_Float16*)alloc(SZ);
    _Float16* Vh  = (_Float16*)alloc(SZ);
    _Float16* Vth = (_Float16*)alloc(SZ);
    _Float16* Th  = (_Float16*)alloc(SZ);
    _Float16* KVC = (_Float16*)alloc(SZ);
    _Float16* AO  = (_Float16*)alloc(SZ);

    k_convert<<<4096, 256, 0, stream>>>(x, xb, M_ROWS * D_MODEL);
    k_transpose<<<dim3(128, 32), 256, 0, stream>>>(Wqkvt, wt, D_MODEL, 4 * D_MODEL);
    k_transpose<<<dim3(32, 32), 256, 0, stream>>>(Wout, wo, D_MODEL, D_MODEL);
    k_gemm<0><<<dim3(32, 32), 256, 0, stream>>>(xb, wt, M_ROWS, 4 * D_MODEL, D_MODEL,
                                                bqkvt, Qh, Kh, Vh, Vth, Th, nullptr);
    k_kvcum<<<BH_TOT, 256, 0, stream>>>(Kh, Vh, KVC);
    k_attn<<<dim3(BH_TOT, NT / 2), 256, 0, stream>>>(Qh, Kh, KVC, Vth, Th, AO);
    k_gemm<1><<<dim3(32, 8), 256, 0, stream>>>(AO, wo, M_ROWS, D_MODEL, D_MODEL,
                                               bout, nullptr, nullptr, nullptr, nullptr,
                                               nullptr, out);
}

// Round 3
// 317.002 us; speedup vs baseline: 1.4674x; 1.0483x over previous
//
#include <hip/hip_runtime.h>

#define T_SEQ 2048
#define D_MODEL 1024
#define NH 16
#define HD 64
#define BH_TOT 32          // B*H
#define M_ROWS 4096        // B*T
#define NT 32              // number of 64-row q tiles
#define SCALE 0.125f
#define BHT (BH_TOT * T_SEQ)

typedef _Float16 h8 __attribute__((ext_vector_type(8)));
typedef _Float16 h4 __attribute__((ext_vector_type(4)));
typedef float f32x4 __attribute__((ext_vector_type(4)));

__device__ __forceinline__ f32x4 mfma_h(h8 a, h8 b, f32x4 c) {
    return __builtin_amdgcn_mfma_f32_16x16x32_f16(a, b, c, 0, 0, 0);
}

// ---------------- convert f32 -> f16 (flat) ----------------
__global__ void k_convert(const float* __restrict__ in, _Float16* __restrict__ out, int n) {
    int i = (blockIdx.x * blockDim.x + threadIdx.x) * 4;
    if (i < n) {
        float4 v = *(const float4*)(in + i);
        h4 o;
        o[0] = (_Float16)v.x; o[1] = (_Float16)v.y;
        o[2] = (_Float16)v.z; o[3] = (_Float16)v.w;
        *(h4*)(out + i) = o;
    }
}

// ---------------- transpose+convert: in [K][N] f32 -> out [N][K] f16 ----------------
__global__ void k_transpose(const float* __restrict__ in, _Float16* __restrict__ out, int K, int N) {
    __shared__ float tile[32][33];
    int nb = blockIdx.x * 32, kb = blockIdx.y * 32;
    int tx = threadIdx.x & 31, ty = threadIdx.x >> 5;   // 256 thr: ty 0..7
    #pragma unroll
    for (int i = 0; i < 32; i += 8)
        tile[ty + i][tx] = in[(size_t)(kb + ty + i) * N + (nb + tx)];
    __syncthreads();
    #pragma unroll
    for (int i = 0; i < 32; i += 8)
        out[(size_t)(nb + ty + i) * K + (kb + tx)] = (_Float16)tile[tx][ty + i];
}

// ---------------- GEMM: C = A[M,K] @ Bt[N,K]^T + bias ----------------
template<int MODE>
__launch_bounds__(256, 2)
__global__ void k_gemm(const _Float16* __restrict__ A, const _Float16* __restrict__ Bt,
                       int M, int N, int K, const float* __restrict__ bias,
                       _Float16* __restrict__ qo, _Float16* __restrict__ ko,
                       _Float16* __restrict__ vo, _Float16* __restrict__ vto,
                       _Float16* __restrict__ to, float* __restrict__ cOut)
{
    constexpr int LDT = 40;
    __shared__ __align__(16) _Float16 lA[128 * LDT];
    __shared__ __align__(16) _Float16 lB[128 * LDT];
    const int tid = threadIdx.x;
    const int wid = tid >> 6, lane = tid & 63, lrow = lane & 15, lg = lane >> 4;
    const int wm = wid >> 1, wn = wid & 1;
    const int m0 = blockIdx.x * 128, n0 = blockIdx.y * 128;

    f32x4 acc[4][4];
    #pragma unroll
    for (int i = 0; i < 4; i++)
        #pragma unroll
        for (int j = 0; j < 4; j++) acc[i][j] = (f32x4){0.f, 0.f, 0.f, 0.f};

    const int srow = tid >> 1, scol = (tid & 1) * 16;
    const _Float16* ga = A + (size_t)(m0 + srow) * K + scol;
    const _Float16* gb = Bt + (size_t)(n0 + srow) * K + scol;

    h8 ra0 = *(const h8*)ga, ra1 = *(const h8*)(ga + 8);
    h8 rb0 = *(const h8*)gb, rb1 = *(const h8*)(gb + 8);
    const int nk = K / 32;
    for (int kt = 0; kt < nk; ++kt) {
        *(h8*)&lA[srow * LDT + scol]     = ra0;
        *(h8*)&lA[srow * LDT + scol + 8] = ra1;
        *(h8*)&lB[srow * LDT + scol]     = rb0;
        *(h8*)&lB[srow * LDT + scol + 8] = rb1;
        __syncthreads();
        if (kt + 1 < nk) {
            ra0 = *(const h8*)(ga + (kt + 1) * 32);
            ra1 = *(const h8*)(ga + (kt + 1) * 32 + 8);
            rb0 = *(const h8*)(gb + (kt + 1) * 32);
            rb1 = *(const h8*)(gb + (kt + 1) * 32 + 8);
        }
        h8 af[4], bfr[4];
        #pragma unroll
        for (int mi = 0; mi < 4; mi++)
            af[mi] = *(const h8*)&lA[(wm * 64 + mi * 16 + lrow) * LDT + lg * 8];
        #pragma unroll
        for (int ni = 0; ni < 4; ni++)
            bfr[ni] = *(const h8*)&lB[(wn * 64 + ni * 16 + lrow) * LDT + lg * 8];
        #pragma unroll
        for (int mi = 0; mi < 4; mi++)
            #pragma unroll
            for (int ni = 0; ni < 4; ni++)
                acc[mi][ni] = mfma_h(af[mi], bfr[ni], acc[mi][ni]);
        __syncthreads();
    }

    if (MODE == 0) {
        const int ssel = n0 >> 10;
        #pragma unroll
        for (int mi = 0; mi < 4; mi++) {
            #pragma unroll
            for (int ni = 0; ni < 4; ni++) {
                const int nn = n0 + wn * 64 + ni * 16 + lrow;
                const float bv = bias[nn];
                const int h = (nn >> 6) & 15, hd = nn & 63;
                #pragma unroll
                for (int r = 0; r < 4; r++) {
                    const int mm = m0 + wm * 64 + mi * 16 + 4 * lg + r;
                    const int b = mm >> 11, t = mm & (T_SEQ - 1);
                    const _Float16 hv = (_Float16)(acc[mi][ni][r] + bv);
                    const size_t idx = ((size_t)(b * NH + h) * T_SEQ + t) * HD + hd;
                    if (ssel == 0) qo[idx] = hv;
                    else if (ssel == 1) ko[idx] = hv;
                    else if (ssel == 2) {
                        vo[idx] = hv;
                        vto[((size_t)(b * NH + h) * HD + hd) * T_SEQ + t] = hv;
                    } else to[idx] = hv;
                }
            }
        }
    } else {
        #pragma unroll
        for (int mi = 0; mi < 4; mi++) {
            #pragma unroll
            for (int ni = 0; ni < 4; ni++) {
                const int nn = n0 + wn * 64 + ni * 16 + lrow;
                const float bv = bias[nn];
                #pragma unroll
                for (int r = 0; r < 4; r++) {
                    const int mm = m0 + wm * 64 + mi * 16 + 4 * lg + r;
                    cOut[(size_t)mm * N + nn] = acc[mi][ni][r] + bv;
                }
            }
        }
    }
}

// ---------------- kv_cum = SCALE * cumsum_t(k*v), per (b,h,d) ----------------
__global__ void k_kvcum(const _Float16* __restrict__ Kb, const _Float16* __restrict__ Vb,
                        _Float16* __restrict__ KVC)
{
    const int bh = blockIdx.x;
    const int w = threadIdx.x >> 6, lane = threadIdx.x & 63;
    const size_t base = (size_t)bh * T_SEQ * HD + lane;
    const int t0 = w * (T_SEQ / 4);
    float s = 0.f;
    for (int i = 0; i < T_SEQ / 4; i++) {
        size_t o = base + (size_t)(t0 + i) * HD;
        s += (float)Kb[o] * (float)Vb[o];
    }
    __shared__ float tot[4][64];
    tot[w][lane] = s;
    __syncthreads();
    float acc = 0.f;
    for (int ww = 0; ww < w; ww++) acc += tot[ww][lane];
    for (int i = 0; i < T_SEQ / 4; i++) {
        size_t o = base + (size_t)(t0 + i) * HD;
        acc += (float)Kb[o] * (float)Vb[o];
        KVC[o] = (_Float16)(acc * SCALE);
    }
}

// ---------------- flash attention partial (key-split two-pass) ----------------
// Block (bh, pair, ksel) processes q-tiles {pair, NT-1-pair}, key-half ksel of each.
// Emits unnormalized O (f16) + (m, l) per row. ksel=0 gets ceil(nj/2) tiles, ksel=1 floor.
__launch_bounds__(256, 4)
__global__ void k_attn(const _Float16* __restrict__ Qb, const _Float16* __restrict__ Kb,
                       const _Float16* __restrict__ KVC, const _Float16* __restrict__ Vt,
                       const _Float16* __restrict__ Tb,
                       _Float16* __restrict__ Op0, _Float16* __restrict__ Op1,
                       float* __restrict__ ML)
{
    const int bh = blockIdx.x;
    const int pair = blockIdx.y;
    const int ksel = blockIdx.z;
    const int tid = threadIdx.x;
    const int wid = tid >> 6, lane = tid & 63, lrow = lane & 15, lg = lane >> 4;
    const size_t hb = (size_t)bh * T_SEQ * HD;
    const _Float16* qp = Qb + hb;
    const _Float16* kp = Kb + hb;
    const _Float16* cp = KVC + hb;
    const _Float16* tp = Tb + hb;
    const _Float16* vp = Vt + hb;    // [HD][T]
    _Float16* op = ksel ? Op1 : Op0;
    float* ml = ML + (size_t)ksel * BHT * 2;

    __shared__ __align__(16) _Float16 lP[4][16 * 64];  // per-wave P buffer (swizzled)

    for (int half = 0; half < 2; ++half) {
        const int qi = half ? (NT - 1 - pair) : pair;
        const int q0 = qi * 64;
        const int nj = qi + 1;
        const int n0 = (nj + 1) >> 1;
        const int jbeg = ksel ? n0 : 0;
        const int jend = ksel ? nj : n0;

        // hoisted Q / Q*T fragments, pre-scaled by SCALE
        const int qrow = q0 + wid * 16 + lrow;
        h8 qf[2], qtf[2];
        #pragma unroll
        for (int ks = 0; ks < 2; ++ks) {
            h8 qv = *(const h8*)&qp[(size_t)qrow * HD + ks * 32 + lg * 8];
            h8 tv = *(const h8*)&tp[(size_t)qrow * HD + ks * 32 + lg * 8];
            h8 a2, b2;
            #pragma unroll
            for (int i = 0; i < 8; i++) {
                float qq = (float)qv[i] * SCALE;
                a2[i] = (_Float16)qq;
                b2[i] = (_Float16)(qq * (float)tv[i]);
            }
            qf[ks] = a2; qtf[ks] = b2;
        }

        float m_r[4], l_r[4];
        f32x4 o[4];
        #pragma unroll
        for (int r = 0; r < 4; r++) { m_r[r] = -__builtin_inff(); l_r[r] = 0.f; }
        #pragma unroll
        for (int ct = 0; ct < 4; ct++) o[ct] = (f32x4){0.f, 0.f, 0.f, 0.f};

        for (int j = jbeg; j < jend; ++j) {
            f32x4 s[4];
            #pragma unroll
            for (int ct = 0; ct < 4; ct++) s[ct] = (f32x4){0.f, 0.f, 0.f, 0.f};
            #pragma unroll
            for (int ct = 0; ct < 4; ct++) {
                const int krow = j * 64 + ct * 16 + lrow;
                #pragma unroll
                for (int ks = 0; ks < 2; ks++) {
                    h8 kf = *(const h8*)&kp[(size_t)krow * HD + ks * 32 + lg * 8];
                    s[ct] = mfma_h(qf[ks], kf, s[ct]);
                    h8 cf = *(const h8*)&cp[(size_t)krow * HD + ks * 32 + lg * 8];
                    s[ct] = mfma_h(qtf[ks], cf, s[ct]);
                }
            }
            if (j == qi) {   // diagonal tile: causal mask
                #pragma unroll
                for (int ct = 0; ct < 4; ct++)
                    #pragma unroll
                    for (int r = 0; r < 4; r++) {
                        int key = j * 64 + ct * 16 + lrow;
                        int qr  = q0 + wid * 16 + 4 * lg + r;
                        if (key > qr) s[ct][r] = -__builtin_inff();
                    }
            }
            // row max across 64 keys (16 lanes x 4 col-tiles)
            float mx[4];
            #pragma unroll
            for (int r = 0; r < 4; r++)
                mx[r] = fmaxf(fmaxf(s[0][r], s[1][r]), fmaxf(s[2][r], s[3][r]));
            #pragma unroll
            for (int d = 1; d < 16; d <<= 1)
                #pragma unroll
                for (int r = 0; r < 4; r++) mx[r] = fmaxf(mx[r], __shfl_xor(mx[r], d, 64));

            float mn[4], scl[4], rs[4];
            #pragma unroll
            for (int r = 0; r < 4; r++) {
                mn[r] = fmaxf(m_r[r], mx[r]);
                scl[r] = __expf(m_r[r] - mn[r]);
                rs[r] = 0.f;
            }
            // P = exp(s - m), write to swizzled LDS (wave-private)
            #pragma unroll
            for (int ct = 0; ct < 4; ct++) {
                const int col = ct * 16 + lrow;
                #pragma unroll
                for (int r = 0; r < 4; r++) {
                    float p = __expf(s[ct][r] - mn[r]);
                    rs[r] += p;
                    const int row = 4 * lg + r;
                    const int boff = row * 128 + ((col * 2) ^ ((row & 7) << 4));
                    lP[wid][boff >> 1] = (_Float16)p;
                }
            }
            #pragma unroll
            for (int d = 1; d < 16; d <<= 1)
                #pragma unroll
                for (int r = 0; r < 4; r++) rs[r] += __shfl_xor(rs[r], d, 64);
            #pragma unroll
            for (int r = 0; r < 4; r++) { l_r[r] = l_r[r] * scl[r] + rs[r]; m_r[r] = mn[r]; }
            #pragma unroll
            for (int ct = 0; ct < 4; ct++)
                #pragma unroll
                for (int r = 0; r < 4; r++) o[ct][r] *= scl[r];

            // P fragments (A-layout) from swizzled LDS
            h8 pa[2];
            #pragma unroll
            for (int ks = 0; ks < 2; ks++) {
                const int boff = lrow * 128 + ((ks * 64 + lg * 16) ^ ((lrow & 7) << 4));
                pa[ks] = *(const h8*)((const char*)lP[wid] + boff);
            }
            // O += P @ V
            #pragma unroll
            for (int ct = 0; ct < 4; ct++) {
                #pragma unroll
                for (int ks = 0; ks < 2; ks++) {
                    h8 vf = *(const h8*)&vp[(size_t)(ct * 16 + lrow) * T_SEQ + j * 64 + ks * 32 + lg * 8];
                    o[ct] = mfma_h(pa[ks], vf, o[ct]);
                }
            }
        }
        // write partial: unnormalized O (f16) + per-row (m, l)
        #pragma unroll
        for (int ct = 0; ct < 4; ct++)
            #pragma unroll
            for (int r = 0; r < 4; r++) {
                const int trow = q0 + wid * 16 + 4 * lg + r;
                const int d = ct * 16 + lrow;
                op[((size_t)bh * T_SEQ + trow) * HD + d] = (_Float16)o[ct][r];
            }
        if (lrow == 0) {
            #pragma unroll
            for (int r = 0; r < 4; r++) {
                const int trow = q0 + wid * 16 + 4 * lg + r;
                const size_t mi = ((size_t)bh * T_SEQ + trow) * 2;
                ml[mi] = m_r[r];
                ml[mi + 1] = l_r[r];
            }
        }
    }
}

// ---------------- combine two key-half partials -> AO [B,T,D] f16 ----------------
__global__ void k_combine(const _Float16* __restrict__ Op0, const _Float16* __restrict__ Op1,
                          const float* __restrict__ ML, _Float16* __restrict__ AO)
{
    const int idx = blockIdx.x * 256 + threadIdx.x;   // over BHT*HD/8
    const int row = idx >> 3;           // bh*T + t
    const int d0 = (idx & 7) * 8;
    const int bh = row >> 11, t = row & (T_SEQ - 1);
    const int b = bh >> 4, h = bh & 15;
    const float m0 = ML[2 * row], l0 = ML[2 * row + 1];
    const float m1 = ML[2 * (BHT + row)], l1 = ML[2 * (BHT + row) + 1];
    const float m = fmaxf(m0, m1);
    const float w0 = __expf(m0 - m), w1 = __expf(m1 - m);
    const float inv = 1.0f / (w0 * l0 + w1 * l1);
    h8 a = *(const h8*)&Op0[(size_t)row * HD + d0];
    h8 c = *(const h8*)&Op1[(size_t)row * HD + d0];
    h8 r;
    #pragma unroll
    for (int i = 0; i < 8; i++)
        r[i] = (_Float16)((w0 * (float)a[i] + w1 * (float)c[i]) * inv);
    *(h8*)&AO[((size_t)(b * T_SEQ + t)) * D_MODEL + h * HD + d0] = r;
}

extern "C" void kernel_launch(void* const* d_in, const int* in_sizes, int n_in,
                              void* d_out, int out_size, void* d_ws, size_t ws_size,
                              hipStream_t stream)
{
    const float* x     = (const float*)d_in[0];
    const float* Wqkvt = (const float*)d_in[1];
    const float* bqkvt = (const float*)d_in[2];
    const float* Wout  = (const float*)d_in[3];
    const float* bout  = (const float*)d_in[4];
    float* out = (float*)d_out;

    char* ws = (char*)d_ws;
    size_t off = 0;
    auto alloc = [&](size_t bytes) {
        char* p = ws + off;
        off += (bytes + 255) & ~(size_t)255;
        return p;
    };
    const size_t SZ = (size_t)M_ROWS * D_MODEL * 2;   // 8 MiB per f16 buffer
    _Float16* xb  = (_Float16*)alloc(SZ);
    _Float16* wt  = (_Float16*)alloc(SZ);
    _Float16* wo  = (_Float16*)alloc((size_t)D_MODEL * D_MODEL * 2);
    _Float16* Qh  = (_Float16*)alloc(SZ);
    _Float16* Kh  = (_Float16*)alloc(SZ);
    _Float16* Vh  = (_Float16*)alloc(SZ);
    _Float16* Vth = (_Float16*)alloc(SZ);
    _Float16* Th  = (_Float16*)alloc(SZ);
    _Float16* KVC = (_Float16*)alloc(SZ);
    _Float16* AO  = (_Float16*)alloc(SZ);

    // aliases (dead after their producers/consumers):
    _Float16* Op0 = xb;            // xb only read by gemm1
    _Float16* Op1 = Vh;            // Vh only read by kvcum
    float*    ML  = (float*)wt;    // wt only read by gemm1 (needs 2 MiB of 8)

    k_convert<<<4096, 256, 0, stream>>>(x, xb, M_ROWS * D_MODEL);
    k_transpose<<<dim3(128, 32), 256, 0, stream>>>(Wqkvt, wt, D_MODEL, 4 * D_MODEL);
    k_transpose<<<dim3(32, 32), 256, 0, stream>>>(Wout, wo, D_MODEL, D_MODEL);
    k_gemm<0><<<dim3(32, 32), 256, 0, stream>>>(xb, wt, M_ROWS, 4 * D_MODEL, D_MODEL,
                                                bqkvt, Qh, Kh, Vh, Vth, Th, nullptr);
    k_kvcum<<<BH_TOT, 256, 0, stream>>>(Kh, Vh, KVC);
    k_attn<<<dim3(BH_TOT, NT / 2, 2), 256, 0, stream>>>(Qh, Kh, KVC, Vth, Th, Op0, Op1, ML);
    k_combine<<<BHT * HD / 8 / 256, 256, 0, stream>>>(Op0, Op1, ML, AO);
    k_gemm<1><<<dim3(32, 8), 256, 0, stream>>>(AO, wo, M_ROWS, D_MODEL, D_MODEL,
                                               bout, nullptr, nullptr, nullptr, nullptr,
                                               nullptr, out);
}

// Round 4
// 308.097 us; speedup vs baseline: 1.5099x; 1.0289x over previous
//
#include <hip/hip_runtime.h>

#define T_SEQ 2048
#define D_MODEL 1024
#define NH 16
#define HD 64
#define BH_TOT 32          // B*H
#define M_ROWS 4096        // B*T
#define NT 32              // number of 64-row q tiles
#define SCALE 0.125f
#define BHT (BH_TOT * T_SEQ)
#define LOG2E 1.44269504f
#define TAU 2.885f         // defer-max threshold in log2 units (= e^2 in p-space)

typedef _Float16 h8 __attribute__((ext_vector_type(8)));
typedef _Float16 h4 __attribute__((ext_vector_type(4)));
typedef float f32x4 __attribute__((ext_vector_type(4)));

__device__ __forceinline__ f32x4 mfma_h(h8 a, h8 b, f32x4 c) {
    return __builtin_amdgcn_mfma_f32_16x16x32_f16(a, b, c, 0, 0, 0);
}

// ---------------- convert f32 -> f16 (flat) ----------------
__global__ void k_convert(const float* __restrict__ in, _Float16* __restrict__ out, int n) {
    int i = (blockIdx.x * blockDim.x + threadIdx.x) * 4;
    if (i < n) {
        float4 v = *(const float4*)(in + i);
        h4 o;
        o[0] = (_Float16)v.x; o[1] = (_Float16)v.y;
        o[2] = (_Float16)v.z; o[3] = (_Float16)v.w;
        *(h4*)(out + i) = o;
    }
}

// ---------------- transpose+convert: in [K][N] f32 -> out [N][K] f16 ----------------
__global__ void k_transpose(const float* __restrict__ in, _Float16* __restrict__ out, int K, int N) {
    __shared__ float tile[32][33];
    int nb = blockIdx.x * 32, kb = blockIdx.y * 32;
    int tx = threadIdx.x & 31, ty = threadIdx.x >> 5;   // 256 thr: ty 0..7
    #pragma unroll
    for (int i = 0; i < 32; i += 8)
        tile[ty + i][tx] = in[(size_t)(kb + ty + i) * N + (nb + tx)];
    __syncthreads();
    #pragma unroll
    for (int i = 0; i < 32; i += 8)
        out[(size_t)(nb + ty + i) * K + (kb + tx)] = (_Float16)tile[tx][ty + i];
}

// ---------------- GEMM: C = A[M,K] @ Bt[N,K]^T + bias ----------------
// MODE 0: scatter epilogue: q->Qh, k->Ke[t][0:64], v->Vh+Vth, t->Th
// MODE 1: plain f32 output C[M,N] + bias
template<int MODE>
__launch_bounds__(256, 2)
__global__ void k_gemm(const _Float16* __restrict__ A, const _Float16* __restrict__ Bt,
                       int M, int N, int K, const float* __restrict__ bias,
                       _Float16* __restrict__ qo, _Float16* __restrict__ keo,
                       _Float16* __restrict__ vo, _Float16* __restrict__ vto,
                       _Float16* __restrict__ to, float* __restrict__ cOut)
{
    constexpr int LDT = 40;
    __shared__ __align__(16) _Float16 lA[128 * LDT];
    __shared__ __align__(16) _Float16 lB[128 * LDT];
    const int tid = threadIdx.x;
    const int wid = tid >> 6, lane = tid & 63, lrow = lane & 15, lg = lane >> 4;
    const int wm = wid >> 1, wn = wid & 1;
    const int m0 = blockIdx.x * 128, n0 = blockIdx.y * 128;

    f32x4 acc[4][4];
    #pragma unroll
    for (int i = 0; i < 4; i++)
        #pragma unroll
        for (int j = 0; j < 4; j++) acc[i][j] = (f32x4){0.f, 0.f, 0.f, 0.f};

    const int srow = tid >> 1, scol = (tid & 1) * 16;
    const _Float16* ga = A + (size_t)(m0 + srow) * K + scol;
    const _Float16* gb = Bt + (size_t)(n0 + srow) * K + scol;

    h8 ra0 = *(const h8*)ga, ra1 = *(const h8*)(ga + 8);
    h8 rb0 = *(const h8*)gb, rb1 = *(const h8*)(gb + 8);
    const int nk = K / 32;
    for (int kt = 0; kt < nk; ++kt) {
        *(h8*)&lA[srow * LDT + scol]     = ra0;
        *(h8*)&lA[srow * LDT + scol + 8] = ra1;
        *(h8*)&lB[srow * LDT + scol]     = rb0;
        *(h8*)&lB[srow * LDT + scol + 8] = rb1;
        __syncthreads();
        if (kt + 1 < nk) {
            ra0 = *(const h8*)(ga + (kt + 1) * 32);
            ra1 = *(const h8*)(ga + (kt + 1) * 32 + 8);
            rb0 = *(const h8*)(gb + (kt + 1) * 32);
            rb1 = *(const h8*)(gb + (kt + 1) * 32 + 8);
        }
        h8 af[4], bfr[4];
        #pragma unroll
        for (int mi = 0; mi < 4; mi++)
            af[mi] = *(const h8*)&lA[(wm * 64 + mi * 16 + lrow) * LDT + lg * 8];
        #pragma unroll
        for (int ni = 0; ni < 4; ni++)
            bfr[ni] = *(const h8*)&lB[(wn * 64 + ni * 16 + lrow) * LDT + lg * 8];
        #pragma unroll
        for (int mi = 0; mi < 4; mi++)
            #pragma unroll
            for (int ni = 0; ni < 4; ni++)
                acc[mi][ni] = mfma_h(af[mi], bfr[ni], acc[mi][ni]);
        __syncthreads();
    }

    if (MODE == 0) {
        const int ssel = n0 >> 10;
        #pragma unroll
        for (int mi = 0; mi < 4; mi++) {
            #pragma unroll
            for (int ni = 0; ni < 4; ni++) {
                const int nn = n0 + wn * 64 + ni * 16 + lrow;
                const float bv = bias[nn];
                const int h = (nn >> 6) & 15, hd = nn & 63;
                #pragma unroll
                for (int r = 0; r < 4; r++) {
                    const int mm = m0 + wm * 64 + mi * 16 + 4 * lg + r;
                    const int b = mm >> 11, t = mm & (T_SEQ - 1);
                    const _Float16 hv = (_Float16)(acc[mi][ni][r] + bv);
                    const size_t row = (size_t)(b * NH + h) * T_SEQ + t;
                    if (ssel == 0) qo[row * HD + hd] = hv;
                    else if (ssel == 1) keo[row * 128 + hd] = hv;
                    else if (ssel == 2) {
                        vo[row * HD + hd] = hv;
                        vto[((size_t)(b * NH + h) * HD + hd) * T_SEQ + t] = hv;
                    } else to[row * HD + hd] = hv;
                }
            }
        }
    } else {
        #pragma unroll
        for (int mi = 0; mi < 4; mi++) {
            #pragma unroll
            for (int ni = 0; ni < 4; ni++) {
                const int nn = n0 + wn * 64 + ni * 16 + lrow;
                const float bv = bias[nn];
                #pragma unroll
                for (int r = 0; r < 4; r++) {
                    const int mm = m0 + wm * 64 + mi * 16 + 4 * lg + r;
                    cOut[(size_t)mm * N + nn] = acc[mi][ni][r] + bv;
                }
            }
        }
    }
}

// ---------------- kv_cum: Ke[t][64+d] = SCALE * cumsum_t(Ke[t][d] * Vh[t][d]) ----------------
__global__ void k_kvcum(_Float16* __restrict__ Ke, const _Float16* __restrict__ Vb)
{
    const int bh = blockIdx.x;
    const int w = threadIdx.x >> 6, lane = threadIdx.x & 63;   // 16 waves
    const size_t bk = (size_t)bh * T_SEQ * 128 + lane;
    const size_t bv = (size_t)bh * T_SEQ * HD + lane;
    const int CH = T_SEQ / 16;
    const int t0 = w * CH;
    float s = 0.f;
    for (int i = 0; i < CH; i++)
        s += (float)Ke[bk + (size_t)(t0 + i) * 128] * (float)Vb[bv + (size_t)(t0 + i) * HD];
    __shared__ float tot[16][64];
    tot[w][lane] = s;
    __syncthreads();
    float acc = 0.f;
    for (int ww = 0; ww < w; ww++) acc += tot[ww][lane];
    for (int i = 0; i < CH; i++) {
        size_t ok = bk + (size_t)(t0 + i) * 128;
        acc += (float)Ke[ok] * (float)Vb[bv + (size_t)(t0 + i) * HD];
        Ke[ok + 64] = (_Float16)(acc * SCALE);
    }
}

// ---------------- flash attention partial (key-split) ----------------
// scores(log2 units) = (C*q | C*q*t) . (k | kvc), C = SCALE*log2e
// Block (bh, pair, ksel): q-tiles {pair, NT-1-pair}, key-chunk ksel of nsplit.
// Deferred-max online softmax; row-sum via ones-MFMA; partial O (f16) + (m2, l).
__launch_bounds__(256, 4)
__global__ void k_attn(const _Float16* __restrict__ Qb, const _Float16* __restrict__ Ke,
                       const _Float16* __restrict__ Vt, const _Float16* __restrict__ Tb,
                       _Float16* __restrict__ Op0, _Float16* __restrict__ Op1,
                       _Float16* __restrict__ Op2, _Float16* __restrict__ Op3,
                       float* __restrict__ ML, int nsplit)
{
    const int bh = blockIdx.x;
    const int pair = blockIdx.y;
    const int ksel = blockIdx.z;
    const int tid = threadIdx.x;
    const int wid = tid >> 6, lane = tid & 63, lrow = lane & 15, lg = lane >> 4;
    const _Float16* qp = Qb + (size_t)bh * T_SEQ * HD;
    const _Float16* kep = Ke + (size_t)bh * T_SEQ * 128;
    const _Float16* tp = Tb + (size_t)bh * T_SEQ * HD;
    const _Float16* vp = Vt + (size_t)bh * T_SEQ * HD;   // [HD][T]
    _Float16* op = (ksel == 0) ? Op0 : (ksel == 1) ? Op1 : (ksel == 2) ? Op2 : Op3;
    float* ml = ML + (size_t)ksel * BHT * 2;

    __shared__ __align__(16) _Float16 lP[4][16 * 64];  // per-wave P buffer (swizzled)

    const h8 ones = {(_Float16)1.f, (_Float16)1.f, (_Float16)1.f, (_Float16)1.f,
                     (_Float16)1.f, (_Float16)1.f, (_Float16)1.f, (_Float16)1.f};
    const float C = SCALE * LOG2E;

    for (int half = 0; half < 2; ++half) {
        const int qi = half ? (NT - 1 - pair) : pair;
        const int q0 = qi * 64;
        const int nj = qi + 1;
        const int jbeg = (nj * ksel) / nsplit;
        const int jend = (nj * (ksel + 1)) / nsplit;

        // hoisted extended-Q fragments: ks 0,1 = C*q chunks; ks 2,3 = C*q*t chunks
        const int qrow = q0 + wid * 16 + lrow;
        h8 qf[4];
        #pragma unroll
        for (int ks = 0; ks < 2; ++ks) {
            h8 qv = *(const h8*)&qp[(size_t)qrow * HD + ks * 32 + lg * 8];
            h8 tv = *(const h8*)&tp[(size_t)qrow * HD + ks * 32 + lg * 8];
            h8 a2, b2;
            #pragma unroll
            for (int i = 0; i < 8; i++) {
                float qq = (float)qv[i] * C;
                a2[i] = (_Float16)qq;
                b2[i] = (_Float16)(qq * (float)tv[i]);
            }
            qf[ks] = a2; qf[2 + ks] = b2;
        }

        float m_r[4];
        f32x4 o[4], o4;
        #pragma unroll
        for (int r = 0; r < 4; r++) m_r[r] = -__builtin_inff();
        #pragma unroll
        for (int ct = 0; ct < 4; ct++) o[ct] = (f32x4){0.f, 0.f, 0.f, 0.f};
        o4 = (f32x4){0.f, 0.f, 0.f, 0.f};

        for (int j = jbeg; j < jend; ++j) {
            f32x4 s[4];
            #pragma unroll
            for (int ct = 0; ct < 4; ct++) {
                const int krow = j * 64 + ct * 16 + lrow;
                const _Float16* kb = &kep[(size_t)krow * 128 + lg * 8];
                f32x4 sv = (f32x4){0.f, 0.f, 0.f, 0.f};
                sv = mfma_h(qf[0], *(const h8*)kb, sv);
                sv = mfma_h(qf[1], *(const h8*)(kb + 32), sv);
                sv = mfma_h(qf[2], *(const h8*)(kb + 64), sv);
                sv = mfma_h(qf[3], *(const h8*)(kb + 96), sv);
                s[ct] = sv;
            }
            if (j == qi) {   // diagonal tile: causal mask
                #pragma unroll
                for (int ct = 0; ct < 4; ct++)
                    #pragma unroll
                    for (int r = 0; r < 4; r++) {
                        int key = j * 64 + ct * 16 + lrow;
                        int qr  = q0 + wid * 16 + 4 * lg + r;
                        if (key > qr) s[ct][r] = -__builtin_inff();
                    }
            }
            // deferred max: only reduce/rescale when some score exceeds m + TAU
            float mx[4];
            #pragma unroll
            for (int r = 0; r < 4; r++)
                mx[r] = fmaxf(fmaxf(s[0][r], s[1][r]), fmaxf(s[2][r], s[3][r]));
            bool need = (mx[0] > m_r[0] + TAU) | (mx[1] > m_r[1] + TAU) |
                        (mx[2] > m_r[2] + TAU) | (mx[3] > m_r[3] + TAU);
            if (__any(need)) {
                #pragma unroll
                for (int d = 1; d < 16; d <<= 1)
                    #pragma unroll
                    for (int r = 0; r < 4; r++) mx[r] = fmaxf(mx[r], __shfl_xor(mx[r], d, 64));
                #pragma unroll
                for (int r = 0; r < 4; r++) {
                    float mn = fmaxf(m_r[r], mx[r]);
                    float scl = __builtin_amdgcn_exp2f(m_r[r] - mn);
                    o[0][r] *= scl; o[1][r] *= scl; o[2][r] *= scl; o[3][r] *= scl;
                    o4[r] *= scl;
                    m_r[r] = mn;
                }
            }
            // P = exp2(s - m) -> swizzled wave-private LDS
            #pragma unroll
            for (int ct = 0; ct < 4; ct++) {
                const int col = ct * 16 + lrow;
                #pragma unroll
                for (int r = 0; r < 4; r++) {
                    float p = __builtin_amdgcn_exp2f(s[ct][r] - m_r[r]);
                    const int row = 4 * lg + r;
                    const int boff = row * 128 + ((col * 2) ^ ((row & 7) << 4));
                    lP[wid][boff >> 1] = (_Float16)p;
                }
            }
            // P fragments (A-layout) from swizzled LDS
            h8 pa[2];
            #pragma unroll
            for (int ks = 0; ks < 2; ks++) {
                const int boff = lrow * 128 + ((ks * 64 + lg * 16) ^ ((lrow & 7) << 4));
                pa[ks] = *(const h8*)((const char*)lP[wid] + boff);
            }
            // O += P @ V ; row-sum l via ones-MFMA (all cols identical)
            o4 = mfma_h(pa[0], ones, o4);
            o4 = mfma_h(pa[1], ones, o4);
            #pragma unroll
            for (int ct = 0; ct < 4; ct++) {
                #pragma unroll
                for (int ks = 0; ks < 2; ks++) {
                    h8 vf = *(const h8*)&vp[(size_t)(ct * 16 + lrow) * T_SEQ + j * 64 + ks * 32 + lg * 8];
                    o[ct] = mfma_h(pa[ks], vf, o[ct]);
                }
            }
        }
        // write partial: unnormalized O (f16) + per-row (m2, l)
        #pragma unroll
        for (int ct = 0; ct < 4; ct++)
            #pragma unroll
            for (int r = 0; r < 4; r++) {
                const int trow = q0 + wid * 16 + 4 * lg + r;
                const int d = ct * 16 + lrow;
                op[((size_t)bh * T_SEQ + trow) * HD + d] = (_Float16)o[ct][r];
            }
        if (lrow == 0) {
            #pragma unroll
            for (int r = 0; r < 4; r++) {
                const int trow = q0 + wid * 16 + 4 * lg + r;
                const size_t mi = ((size_t)bh * T_SEQ + trow) * 2;
                ml[mi] = m_r[r];
                ml[mi + 1] = o4[r];
            }
        }
    }
}

// ---------------- combine nsplit key-chunk partials -> AO [B,T,D] f16 ----------------
__global__ void k_combine(const _Float16* __restrict__ Op0, const _Float16* __restrict__ Op1,
                          const _Float16* __restrict__ Op2, const _Float16* __restrict__ Op3,
                          const float* __restrict__ ML, _Float16* __restrict__ AO, int nsplit)
{
    const int idx = blockIdx.x * 256 + threadIdx.x;   // over BHT*HD/8
    const int row = idx >> 3;           // bh*T + t
    const int d0 = (idx & 7) * 8;
    const int bh = row >> 11, t = row & (T_SEQ - 1);
    const int b = bh >> 4, h = bh & 15;
    const _Float16* ops[4] = {Op0, Op1, Op2, Op3};
    float m = -__builtin_inff();
    for (int c = 0; c < nsplit; c++) m = fmaxf(m, ML[(size_t)c * BHT * 2 + 2 * row]);
    float w[4], denom = 0.f;
    for (int c = 0; c < nsplit; c++) {
        w[c] = __builtin_amdgcn_exp2f(ML[(size_t)c * BHT * 2 + 2 * row] - m);
        denom += w[c] * ML[(size_t)c * BHT * 2 + 2 * row + 1];
    }
    const float inv = 1.0f / denom;
    float accv[8];
    #pragma unroll
    for (int i = 0; i < 8; i++) accv[i] = 0.f;
    for (int c = 0; c < nsplit; c++) {
        h8 a = *(const h8*)&ops[c][(size_t)row * HD + d0];
        #pragma unroll
        for (int i = 0; i < 8; i++) accv[i] += w[c] * (float)a[i];
    }
    h8 r;
    #pragma unroll
    for (int i = 0; i < 8; i++) r[i] = (_Float16)(accv[i] * inv);
    *(h8*)&AO[((size_t)(b * T_SEQ + t)) * D_MODEL + h * HD + d0] = r;
}

extern "C" void kernel_launch(void* const* d_in, const int* in_sizes, int n_in,
                              void* d_out, int out_size, void* d_ws, size_t ws_size,
                              hipStream_t stream)
{
    const float* x     = (const float*)d_in[0];
    const float* Wqkvt = (const float*)d_in[1];
    const float* bqkvt = (const float*)d_in[2];
    const float* Wout  = (const float*)d_in[3];
    const float* bout  = (const float*)d_in[4];
    float* out = (float*)d_out;

    char* ws = (char*)d_ws;
    size_t off = 0;
    auto alloc = [&](size_t bytes) {
        char* p = ws + off;
        off += (bytes + 255) & ~(size_t)255;
        return p;
    };
    const size_t SZ = (size_t)M_ROWS * D_MODEL * 2;   // 8 MiB per f16 [B,H,T,64] buffer
    _Float16* xb  = (_Float16*)alloc(SZ);              // -> Op0 after gemm1
    _Float16* wt  = (_Float16*)alloc(SZ);              // -> ML after gemm1
    _Float16* wo  = (_Float16*)alloc((size_t)D_MODEL * D_MODEL * 2);
    _Float16* Qh  = (_Float16*)alloc(SZ);
    _Float16* Ke  = (_Float16*)alloc(SZ * 2);          // [B,H,T,128] = k | kvc
    _Float16* Vh  = (_Float16*)alloc(SZ);              // -> Op1 after kvcum
    _Float16* Vth = (_Float16*)alloc(SZ);
    _Float16* Th  = (_Float16*)alloc(SZ);
    _Float16* AO  = (_Float16*)alloc(SZ);
    const size_t need4 = off + 2 * SZ;
    _Float16* Op2 = (_Float16*)alloc(SZ);
    _Float16* Op3 = (_Float16*)alloc(SZ);

    const int nsplit = (ws_size >= need4) ? 4 : 2;

    _Float16* Op0 = xb;
    _Float16* Op1 = Vh;
    float*    ML  = (float*)wt;    // nsplit * 512 KiB of 8 MiB

    k_convert<<<4096, 256, 0, stream>>>(x, xb, M_ROWS * D_MODEL);
    k_transpose<<<dim3(128, 32), 256, 0, stream>>>(Wqkvt, wt, D_MODEL, 4 * D_MODEL);
    k_transpose<<<dim3(32, 32), 256, 0, stream>>>(Wout, wo, D_MODEL, D_MODEL);
    k_gemm<0><<<dim3(32, 32), 256, 0, stream>>>(xb, wt, M_ROWS, 4 * D_MODEL, D_MODEL,
                                                bqkvt, Qh, Ke, Vh, Vth, Th, nullptr);
    k_kvcum<<<BH_TOT, 1024, 0, stream>>>(Ke, Vh);
    k_attn<<<dim3(BH_TOT, NT / 2, nsplit), 256, 0, stream>>>(Qh, Ke, Vth, Th,
                                                             Op0, Op1, Op2, Op3, ML, nsplit);
    k_combine<<<BHT * HD / 8 / 256, 256, 0, stream>>>(Op0, Op1, Op2, Op3, ML, AO, nsplit);
    k_gemm<1><<<dim3(32, 8), 256, 0, stream>>>(AO, wo, M_ROWS, D_MODEL, D_MODEL,
                                               bout, nullptr, nullptr, nullptr, nullptr,
                                               nullptr, out);
}

// Round 5
// 190.493 us; speedup vs baseline: 2.4420x; 1.6174x over previous
//
#include <hip/hip_runtime.h>

#define T_SEQ 2048
#define D_MODEL 1024
#define NH 16
#define HD 64
#define BH_TOT 32          // B*H
#define M_ROWS 4096        // B*T
#define NT 32              // number of 64-row q tiles
#define SCALE 0.125f
#define BHT (BH_TOT * T_SEQ)
#define LOG2E 1.44269504f
#define TAU 2.885f         // defer-max threshold in log2 units (= e^2 in p-space)

typedef _Float16 h8 __attribute__((ext_vector_type(8)));
typedef _Float16 h4 __attribute__((ext_vector_type(4)));
typedef float f32x4 __attribute__((ext_vector_type(4)));

__device__ __forceinline__ f32x4 mfma_h(h8 a, h8 b, f32x4 c) {
    return __builtin_amdgcn_mfma_f32_16x16x32_f16(a, b, c, 0, 0, 0);
}

// ---------------- convert f32 -> f16 (flat) ----------------
__global__ void k_convert(const float* __restrict__ in, _Float16* __restrict__ out, int n) {
    int i = (blockIdx.x * blockDim.x + threadIdx.x) * 4;
    if (i < n) {
        float4 v = *(const float4*)(in + i);
        h4 o;
        o[0] = (_Float16)v.x; o[1] = (_Float16)v.y;
        o[2] = (_Float16)v.z; o[3] = (_Float16)v.w;
        *(h4*)(out + i) = o;
    }
}

// ---------------- transpose+convert: in [K][N] f32 -> out [N][K] f16 ----------------
__global__ void k_transpose(const float* __restrict__ in, _Float16* __restrict__ out, int K, int N) {
    __shared__ float tile[32][33];
    int nb = blockIdx.x * 32, kb = blockIdx.y * 32;
    int tx = threadIdx.x & 31, ty = threadIdx.x >> 5;   // 256 thr: ty 0..7
    #pragma unroll
    for (int i = 0; i < 32; i += 8)
        tile[ty + i][tx] = in[(size_t)(kb + ty + i) * N + (nb + tx)];
    __syncthreads();
    #pragma unroll
    for (int i = 0; i < 32; i += 8)
        out[(size_t)(nb + ty + i) * K + (kb + tx)] = (_Float16)tile[tx][ty + i];
}

// ---------------- GEMM: C = A[M,K] @ Bt[N,K]^T + bias ----------------
// MODE 0: scatter epilogue: q->Qh, k->Ke[t][0:64], v->Vh+Vth, t->Th
// MODE 1: plain f32 output C[M,N] + bias
template<int MODE>
__launch_bounds__(256, 2)
__global__ void k_gemm(const _Float16* __restrict__ A, const _Float16* __restrict__ Bt,
                       int M, int N, int K, const float* __restrict__ bias,
                       _Float16* __restrict__ qo, _Float16* __restrict__ keo,
                       _Float16* __restrict__ vo, _Float16* __restrict__ vto,
                       _Float16* __restrict__ to, float* __restrict__ cOut)
{
    constexpr int LDT = 40;
    __shared__ __align__(16) _Float16 lA[128 * LDT];
    __shared__ __align__(16) _Float16 lB[128 * LDT];
    const int tid = threadIdx.x;
    const int wid = tid >> 6, lane = tid & 63, lrow = lane & 15, lg = lane >> 4;
    const int wm = wid >> 1, wn = wid & 1;
    const int m0 = blockIdx.x * 128, n0 = blockIdx.y * 128;

    f32x4 acc[4][4];
    #pragma unroll
    for (int i = 0; i < 4; i++)
        #pragma unroll
        for (int j = 0; j < 4; j++) acc[i][j] = (f32x4){0.f, 0.f, 0.f, 0.f};

    const int srow = tid >> 1, scol = (tid & 1) * 16;
    const _Float16* ga = A + (size_t)(m0 + srow) * K + scol;
    const _Float16* gb = Bt + (size_t)(n0 + srow) * K + scol;

    h8 ra0 = *(const h8*)ga, ra1 = *(const h8*)(ga + 8);
    h8 rb0 = *(const h8*)gb, rb1 = *(const h8*)(gb + 8);
    const int nk = K / 32;
    for (int kt = 0; kt < nk; ++kt) {
        *(h8*)&lA[srow * LDT + scol]     = ra0;
        *(h8*)&lA[srow * LDT + scol + 8] = ra1;
        *(h8*)&lB[srow * LDT + scol]     = rb0;
        *(h8*)&lB[srow * LDT + scol + 8] = rb1;
        __syncthreads();
        if (kt + 1 < nk) {
            ra0 = *(const h8*)(ga + (kt + 1) * 32);
            ra1 = *(const h8*)(ga + (kt + 1) * 32 + 8);
            rb0 = *(const h8*)(gb + (kt + 1) * 32);
            rb1 = *(const h8*)(gb + (kt + 1) * 32 + 8);
        }
        h8 af[4], bfr[4];
        #pragma unroll
        for (int mi = 0; mi < 4; mi++)
            af[mi] = *(const h8*)&lA[(wm * 64 + mi * 16 + lrow) * LDT + lg * 8];
        #pragma unroll
        for (int ni = 0; ni < 4; ni++)
            bfr[ni] = *(const h8*)&lB[(wn * 64 + ni * 16 + lrow) * LDT + lg * 8];
        #pragma unroll
        for (int mi = 0; mi < 4; mi++)
            #pragma unroll
            for (int ni = 0; ni < 4; ni++)
                acc[mi][ni] = mfma_h(af[mi], bfr[ni], acc[mi][ni]);
        __syncthreads();
    }

    if (MODE == 0) {
        const int ssel = n0 >> 10;
        #pragma unroll
        for (int mi = 0; mi < 4; mi++) {
            #pragma unroll
            for (int ni = 0; ni < 4; ni++) {
                const int nn = n0 + wn * 64 + ni * 16 + lrow;
                const float bv = bias[nn];
                const int h = (nn >> 6) & 15, hd = nn & 63;
                #pragma unroll
                for (int r = 0; r < 4; r++) {
                    const int mm = m0 + wm * 64 + mi * 16 + 4 * lg + r;
                    const int b = mm >> 11, t = mm & (T_SEQ - 1);
                    const _Float16 hv = (_Float16)(acc[mi][ni][r] + bv);
                    const size_t row = (size_t)(b * NH + h) * T_SEQ + t;
                    if (ssel == 0) qo[row * HD + hd] = hv;
                    else if (ssel == 1) keo[row * 128 + hd] = hv;
                    else if (ssel == 2) {
                        vo[row * HD + hd] = hv;
                        vto[((size_t)(b * NH + h) * HD + hd) * T_SEQ + t] = hv;
                    } else to[row * HD + hd] = hv;
                }
            }
        }
    } else {
        #pragma unroll
        for (int mi = 0; mi < 4; mi++) {
            #pragma unroll
            for (int ni = 0; ni < 4; ni++) {
                const int nn = n0 + wn * 64 + ni * 16 + lrow;
                const float bv = bias[nn];
                #pragma unroll
                for (int r = 0; r < 4; r++) {
                    const int mm = m0 + wm * 64 + mi * 16 + 4 * lg + r;
                    cOut[(size_t)mm * N + nn] = acc[mi][ni][r] + bv;
                }
            }
        }
    }
}

// ---------------- kv_cum: Ke[t][64+d] = SCALE * cumsum_t(Ke[t][d] * Vh[t][d]) ----------------
__global__ void k_kvcum(_Float16* __restrict__ Ke, const _Float16* __restrict__ Vb)
{
    const int bh = blockIdx.x;
    const int w = threadIdx.x >> 6, lane = threadIdx.x & 63;   // 16 waves
    const size_t bk = (size_t)bh * T_SEQ * 128 + lane;
    const size_t bv = (size_t)bh * T_SEQ * HD + lane;
    const int CH = T_SEQ / 16;
    const int t0 = w * CH;
    float s = 0.f;
    for (int i = 0; i < CH; i++)
        s += (float)Ke[bk + (size_t)(t0 + i) * 128] * (float)Vb[bv + (size_t)(t0 + i) * HD];
    __shared__ float tot[16][64];
    tot[w][lane] = s;
    __syncthreads();
    float acc = 0.f;
    for (int ww = 0; ww < w; ww++) acc += tot[ww][lane];
    for (int i = 0; i < CH; i++) {
        size_t ok = bk + (size_t)(t0 + i) * 128;
        acc += (float)Ke[ok] * (float)Vb[bv + (size_t)(t0 + i) * HD];
        Ke[ok + 64] = (_Float16)(acc * SCALE);
    }
}

// ---------------- flash attention partial (key-split, LDS-staged tiles) ----------------
// scores(log2 units) = (C*q | C*q*t) . (k | kvc), C = SCALE*log2e
// Per key-tile j: block cooperatively stages Ke-tile (64x128 f16, 16KB) and
// Vt-tile (64x64 f16, 8KB) into XOR-swizzled LDS with coalesced global loads,
// then all 4 waves read MFMA fragments from LDS (<=2-way conflicts).
__launch_bounds__(256, 4)
__global__ void k_attn(const _Float16* __restrict__ Qb, const _Float16* __restrict__ Ke,
                       const _Float16* __restrict__ Vt, const _Float16* __restrict__ Tb,
                       _Float16* __restrict__ Op0, _Float16* __restrict__ Op1,
                       _Float16* __restrict__ Op2, _Float16* __restrict__ Op3,
                       float* __restrict__ ML, int nsplit)
{
    const int bh = blockIdx.x;
    const int pair = blockIdx.y;
    const int ksel = blockIdx.z;
    const int tid = threadIdx.x;
    const int wid = tid >> 6, lane = tid & 63, lrow = lane & 15, lg = lane >> 4;
    const _Float16* qp = Qb + (size_t)bh * T_SEQ * HD;
    const _Float16* kep = Ke + (size_t)bh * T_SEQ * 128;
    const _Float16* tp = Tb + (size_t)bh * T_SEQ * HD;
    const _Float16* vp = Vt + (size_t)bh * T_SEQ * HD;   // [HD][T]
    _Float16* op = (ksel == 0) ? Op0 : (ksel == 1) ? Op1 : (ksel == 2) ? Op2 : Op3;
    float* ml = ML + (size_t)ksel * BHT * 2;

    __shared__ __align__(16) _Float16 ldsK[64 * 128];  // 16 KB, swizzled granules
    __shared__ __align__(16) _Float16 ldsV[64 * 64];   // 8 KB, swizzled granules
    __shared__ __align__(16) _Float16 lP[4][16 * 64];  // 8 KB per-wave P (swizzled)

    // staging coords (block-wide)
    const int kpos = tid & 15, kprow = tid >> 4;   // Ke: 16 granules/row, 16 rows/round
    const int vpos = tid & 7,  vprow = tid >> 3;   // Vt: 8 granules/row, 32 rows/round
    // fragment-read swizzle: row&7 == lrow&7 for all ct (ct*16 multiple of 8)
    const int r7 = lrow & 7;
    int kswz[4];
    #pragma unroll
    for (int c = 0; c < 4; c++) kswz[c] = ((c * 4 + lg) ^ r7) * 8;

    const h8 ones = {(_Float16)1.f, (_Float16)1.f, (_Float16)1.f, (_Float16)1.f,
                     (_Float16)1.f, (_Float16)1.f, (_Float16)1.f, (_Float16)1.f};
    const float C = SCALE * LOG2E;

    for (int half = 0; half < 2; ++half) {
        const int qi = half ? (NT - 1 - pair) : pair;
        const int q0 = qi * 64;
        const int nj = qi + 1;
        const int jbeg = (nj * ksel) / nsplit;
        const int jend = (nj * (ksel + 1)) / nsplit;

        // hoisted extended-Q fragments: ks 0,1 = C*q chunks; ks 2,3 = C*q*t chunks
        const int qrow = q0 + wid * 16 + lrow;
        h8 qf[4];
        #pragma unroll
        for (int ks = 0; ks < 2; ++ks) {
            h8 qv = *(const h8*)&qp[(size_t)qrow * HD + ks * 32 + lg * 8];
            h8 tv = *(const h8*)&tp[(size_t)qrow * HD + ks * 32 + lg * 8];
            h8 a2, b2;
            #pragma unroll
            for (int i = 0; i < 8; i++) {
                float qq = (float)qv[i] * C;
                a2[i] = (_Float16)qq;
                b2[i] = (_Float16)(qq * (float)tv[i]);
            }
            qf[ks] = a2; qf[2 + ks] = b2;
        }

        float m_r[4];
        f32x4 o[4], o4;
        #pragma unroll
        for (int r = 0; r < 4; r++) m_r[r] = -__builtin_inff();
        #pragma unroll
        for (int ct = 0; ct < 4; ct++) o[ct] = (f32x4){0.f, 0.f, 0.f, 0.f};
        o4 = (f32x4){0.f, 0.f, 0.f, 0.f};

        for (int j = jbeg; j < jend; ++j) {
            __syncthreads();   // previous tile fully consumed
            // ---- stage Ke tile: 64 rows x 256B, coalesced, swizzle granule^=(row&7)
            #pragma unroll
            for (int rr = 0; rr < 4; rr++) {
                const int row = rr * 16 + kprow;
                h8 kv = *(const h8*)&kep[(size_t)(j * 64 + row) * 128 + kpos * 8];
                *(h8*)&ldsK[row * 128 + ((kpos ^ (row & 7)) * 8)] = kv;
            }
            // ---- stage Vt tile: 64 rows x 128B, coalesced
            #pragma unroll
            for (int rr = 0; rr < 2; rr++) {
                const int d = rr * 32 + vprow;
                h8 vv = *(const h8*)&vp[(size_t)d * T_SEQ + j * 64 + vpos * 8];
                *(h8*)&ldsV[d * 64 + ((vpos ^ (d & 7)) * 8)] = vv;
            }
            __syncthreads();   // tile visible to all waves

            f32x4 s[4];
            #pragma unroll
            for (int ct = 0; ct < 4; ct++) {
                const _Float16* kb = &ldsK[(ct * 16 + lrow) * 128];
                f32x4 sv = (f32x4){0.f, 0.f, 0.f, 0.f};
                sv = mfma_h(qf[0], *(const h8*)&kb[kswz[0]], sv);
                sv = mfma_h(qf[1], *(const h8*)&kb[kswz[1]], sv);
                sv = mfma_h(qf[2], *(const h8*)&kb[kswz[2]], sv);
                sv = mfma_h(qf[3], *(const h8*)&kb[kswz[3]], sv);
                s[ct] = sv;
            }
            if (j == qi) {   // diagonal tile: causal mask
                #pragma unroll
                for (int ct = 0; ct < 4; ct++)
                    #pragma unroll
                    for (int r = 0; r < 4; r++) {
                        int key = j * 64 + ct * 16 + lrow;
                        int qr  = q0 + wid * 16 + 4 * lg + r;
                        if (key > qr) s[ct][r] = -__builtin_inff();
                    }
            }
            // deferred max: only reduce/rescale when some score exceeds m + TAU
            float mx[4];
            #pragma unroll
            for (int r = 0; r < 4; r++)
                mx[r] = fmaxf(fmaxf(s[0][r], s[1][r]), fmaxf(s[2][r], s[3][r]));
            bool need = (mx[0] > m_r[0] + TAU) | (mx[1] > m_r[1] + TAU) |
                        (mx[2] > m_r[2] + TAU) | (mx[3] > m_r[3] + TAU);
            if (__any(need)) {
                #pragma unroll
                for (int d = 1; d < 16; d <<= 1)
                    #pragma unroll
                    for (int r = 0; r < 4; r++) mx[r] = fmaxf(mx[r], __shfl_xor(mx[r], d, 64));
                #pragma unroll
                for (int r = 0; r < 4; r++) {
                    float mn = fmaxf(m_r[r], mx[r]);
                    float scl = __builtin_amdgcn_exp2f(m_r[r] - mn);
                    o[0][r] *= scl; o[1][r] *= scl; o[2][r] *= scl; o[3][r] *= scl;
                    o4[r] *= scl;
                    m_r[r] = mn;
                }
            }
            // P = exp2(s - m) -> swizzled wave-private LDS
            #pragma unroll
            for (int ct = 0; ct < 4; ct++) {
                const int col = ct * 16 + lrow;
                #pragma unroll
                for (int r = 0; r < 4; r++) {
                    float p = __builtin_amdgcn_exp2f(s[ct][r] - m_r[r]);
                    const int row = 4 * lg + r;
                    const int boff = row * 128 + ((col * 2) ^ ((row & 7) << 4));
                    lP[wid][boff >> 1] = (_Float16)p;
                }
            }
            // P fragments (A-layout) from swizzled LDS
            h8 pa[2];
            #pragma unroll
            for (int ks = 0; ks < 2; ks++) {
                const int boff = lrow * 128 + ((ks * 64 + lg * 16) ^ ((lrow & 7) << 4));
                pa[ks] = *(const h8*)((const char*)lP[wid] + boff);
            }
            // O += P @ V ; row-sum l via ones-MFMA (all cols identical)
            o4 = mfma_h(pa[0], ones, o4);
            o4 = mfma_h(pa[1], ones, o4);
            #pragma unroll
            for (int ct = 0; ct < 4; ct++) {
                const _Float16* vb = &ldsV[(ct * 16 + lrow) * 64];
                o[ct] = mfma_h(pa[0], *(const h8*)&vb[kswz[0]], o[ct]);
                o[ct] = mfma_h(pa[1], *(const h8*)&vb[kswz[1]], o[ct]);
            }
        }
        // write partial: unnormalized O (f16) + per-row (m2, l)
        #pragma unroll
        for (int ct = 0; ct < 4; ct++)
            #pragma unroll
            for (int r = 0; r < 4; r++) {
                const int trow = q0 + wid * 16 + 4 * lg + r;
                const int d = ct * 16 + lrow;
                op[((size_t)bh * T_SEQ + trow) * HD + d] = (_Float16)o[ct][r];
            }
        if (lrow == 0) {
            #pragma unroll
            for (int r = 0; r < 4; r++) {
                const int trow = q0 + wid * 16 + 4 * lg + r;
                const size_t mi = ((size_t)bh * T_SEQ + trow) * 2;
                ml[mi] = m_r[r];
                ml[mi + 1] = o4[r];
            }
        }
    }
}

// ---------------- combine nsplit key-chunk partials -> AO [B,T,D] f16 ----------------
__global__ void k_combine(const _Float16* __restrict__ Op0, const _Float16* __restrict__ Op1,
                          const _Float16* __restrict__ Op2, const _Float16* __restrict__ Op3,
                          const float* __restrict__ ML, _Float16* __restrict__ AO, int nsplit)
{
    const int idx = blockIdx.x * 256 + threadIdx.x;   // over BHT*HD/8
    const int row = idx >> 3;           // bh*T + t
    const int d0 = (idx & 7) * 8;
    const int bh = row >> 11, t = row & (T_SEQ - 1);
    const int b = bh >> 4, h = bh & 15;
    const _Float16* ops[4] = {Op0, Op1, Op2, Op3};
    float m = -__builtin_inff();
    for (int c = 0; c < nsplit; c++) m = fmaxf(m, ML[(size_t)c * BHT * 2 + 2 * row]);
    float w[4], denom = 0.f;
    for (int c = 0; c < nsplit; c++) {
        w[c] = __builtin_amdgcn_exp2f(ML[(size_t)c * BHT * 2 + 2 * row] - m);
        denom += w[c] * ML[(size_t)c * BHT * 2 + 2 * row + 1];
    }
    const float inv = 1.0f / denom;
    float accv[8];
    #pragma unroll
    for (int i = 0; i < 8; i++) accv[i] = 0.f;
    for (int c = 0; c < nsplit; c++) {
        h8 a = *(const h8*)&ops[c][(size_t)row * HD + d0];
        #pragma unroll
        for (int i = 0; i < 8; i++) accv[i] += w[c] * (float)a[i];
    }
    h8 r;
    #pragma unroll
    for (int i = 0; i < 8; i++) r[i] = (_Float16)(accv[i] * inv);
    *(h8*)&AO[((size_t)(b * T_SEQ + t)) * D_MODEL + h * HD + d0] = r;
}

extern "C" void kernel_launch(void* const* d_in, const int* in_sizes, int n_in,
                              void* d_out, int out_size, void* d_ws, size_t ws_size,
                              hipStream_t stream)
{
    const float* x     = (const float*)d_in[0];
    const float* Wqkvt = (const float*)d_in[1];
    const float* bqkvt = (const float*)d_in[2];
    const float* Wout  = (const float*)d_in[3];
    const float* bout  = (const float*)d_in[4];
    float* out = (float*)d_out;

    char* ws = (char*)d_ws;
    size_t off = 0;
    auto alloc = [&](size_t bytes) {
        char* p = ws + off;
        off += (bytes + 255) & ~(size_t)255;
        return p;
    };
    const size_t SZ = (size_t)M_ROWS * D_MODEL * 2;   // 8 MiB per f16 [B,H,T,64] buffer
    _Float16* xb  = (_Float16*)alloc(SZ);              // -> Op0 after gemm1
    _Float16* wt  = (_Float16*)alloc(SZ);              // -> ML after gemm1
    _Float16* wo  = (_Float16*)alloc((size_t)D_MODEL * D_MODEL * 2);
    _Float16* Qh  = (_Float16*)alloc(SZ);
    _Float16* Ke  = (_Float16*)alloc(SZ * 2);          // [B,H,T,128] = k | kvc
    _Float16* Vh  = (_Float16*)alloc(SZ);              // -> Op1 after kvcum
    _Float16* Vth = (_Float16*)alloc(SZ);
    _Float16* Th  = (_Float16*)alloc(SZ);
    _Float16* AO  = (_Float16*)alloc(SZ);
    const size_t need4 = off + 2 * SZ;
    _Float16* Op2 = (_Float16*)alloc(SZ);
    _Float16* Op3 = (_Float16*)alloc(SZ);

    const int nsplit = (ws_size >= need4) ? 4 : 2;

    _Float16* Op0 = xb;
    _Float16* Op1 = Vh;
    float*    ML  = (float*)wt;    // nsplit * 512 KiB of 8 MiB

    k_convert<<<4096, 256, 0, stream>>>(x, xb, M_ROWS * D_MODEL);
    k_transpose<<<dim3(128, 32), 256, 0, stream>>>(Wqkvt, wt, D_MODEL, 4 * D_MODEL);
    k_transpose<<<dim3(32, 32), 256, 0, stream>>>(Wout, wo, D_MODEL, D_MODEL);
    k_gemm<0><<<dim3(32, 32), 256, 0, stream>>>(xb, wt, M_ROWS, 4 * D_MODEL, D_MODEL,
                                                bqkvt, Qh, Ke, Vh, Vth, Th, nullptr);
    k_kvcum<<<BH_TOT, 1024, 0, stream>>>(Ke, Vh);
    k_attn<<<dim3(BH_TOT, NT / 2, nsplit), 256, 0, stream>>>(Qh, Ke, Vth, Th,
                                                             Op0, Op1, Op2, Op3, ML, nsplit);
    k_combine<<<BHT * HD / 8 / 256, 256, 0, stream>>>(Op0, Op1, Op2, Op3, ML, AO, nsplit);
    k_gemm<1><<<dim3(32, 8), 256, 0, stream>>>(AO, wo, M_ROWS, D_MODEL, D_MODEL,
                                               bout, nullptr, nullptr, nullptr, nullptr,
                                               nullptr, out);
}